// Round 3
// baseline (218.673 us; speedup 1.0000x reference)
//
#include <hip/hip_runtime.h>

// Problem constants (reference: N=2048, F=128, HEADS=8, OUT_DIM=8, ALPHA=0.2)
#define NN      2048
#define FDIM    128
#define HEADS   8
#define ODIM    8
#define HID     64      // HEADS*ODIM
#define ALPHA   0.2f

__device__ __forceinline__ float lrelu(float x) {
    return x > 0.f ? x : ALPHA * x;
}

// readfirstlane for float: value must be wave-uniform (it is: per-block row data)
__device__ __forceinline__ float rfl(float x) {
    return __int_as_float(__builtin_amdgcn_readfirstlane(__float_as_int(x)));
}

// ---------------------------------------------------------------------------
// Kernel 1: h = X @ W  (per-node row), s1 = h . a1, s2 = h . a2  (per head)
// grid = NN blocks, block = 64 threads (1 wave)
// ---------------------------------------------------------------------------
__global__ __launch_bounds__(64) void gat_prep(
        const float* __restrict__ X,   // (NN, FDIM)
        const float* __restrict__ W,   // (FDIM, HID)
        const float* __restrict__ ak,  // (2*ODIM,)
        float* __restrict__ H,         // (NN, HID)
        float* __restrict__ S1,        // (NN, HEADS)
        float* __restrict__ S2) {      // (NN, HEADS)
    const int n = blockIdx.x;
    const int t = threadIdx.x;

    __shared__ float Xs[FDIM];
    __shared__ float hs[HID];

    Xs[t]      = X[(size_t)n * FDIM + t];
    Xs[t + 64] = X[(size_t)n * FDIM + 64 + t];
    __syncthreads();

    float acc = 0.f;
    #pragma unroll 8
    for (int k = 0; k < FDIM; ++k)
        acc = fmaf(Xs[k], W[k * HID + t], acc);   // Xs[k]: LDS broadcast; W col: coalesced

    H[(size_t)n * HID + t] = acc;
    hs[t] = acc;
    __syncthreads();

    if (t < 16) {
        const int head = t & 7;
        const float* a = ak + ((t < 8) ? 0 : ODIM);
        float s = 0.f;
        #pragma unroll
        for (int d = 0; d < ODIM; ++d)
            s = fmaf(hs[head * ODIM + d], a[d], s);
        if (t < 8) S1[n * HEADS + head] = s;
        else       S2[n * HEADS + head] = s;
    }
}

// ---------------------------------------------------------------------------
// Kernel 2 (fused, R2 restructure): per row i, block = 512, thread t owns
// j = 4t..4t+3 (one int4 of A held in registers — no LDS staging, no
// staging barrier).
//   pass A: p[e][h] = mask * exp(lrelu(s1[h]+s2[j,h]))  (kept in 32 VGPRs)
//           LF[h]   = block-reduce sum of p               (2 barriers total)
//   pass B: out[i,j,d] = lrelu( sum_h p[e][h] * hh_s[h*8+d] )
// Key pressure fix: hh (H row / LF) and s1 are WAVE-UNIFORM → forced into
// SGPRs via readfirstlane. v_fma with SGPR operand is free; per-thread
// VGPR demand ~70 → no spill possible, 4 waves/EU fits.
// exp computed ONCE (was twice): p survives in registers between passes.
// ---------------------------------------------------------------------------
__global__ __launch_bounds__(512, 4) void gat_fused(
        const int*   __restrict__ A,    // (NN, NN)
        const float* __restrict__ H,    // (NN, HID)
        const float* __restrict__ S1,   // (NN, HEADS)
        const float* __restrict__ S2,   // (NN, HEADS)
        float* __restrict__ out) {      // (NN, NN, ODIM)
    const int i    = blockIdx.x;
    const int t    = threadIdx.x;
    const int wave = t >> 6;
    const int lane = t & 63;

    __shared__ float hhS[HID];
    __shared__ float redL[8 * HEADS];
    __shared__ float LFs[HEADS];

    if (t < HID)
        hhS[t] = H[(size_t)i * HID + t];

    // s1: block-uniform → scalar registers
    float s1r[HEADS];
    #pragma unroll
    for (int h = 0; h < HEADS; ++h)
        s1r[h] = rfl(S1[i * HEADS + h]);

    // A row: thread t owns j = 4t..4t+3, one int4, lives in registers
    const int4 av = ((const int4*)(A + (size_t)i * NN))[t];
    const int aj[4] = {av.x, av.y, av.z, av.w};

    // ---- pass A: compute p once, accumulate denominators ---------------
    float p[4][HEADS];
    float ls[HEADS];
    #pragma unroll
    for (int h = 0; h < HEADS; ++h) ls[h] = 0.f;

    #pragma unroll
    for (int e = 0; e < 4; ++e) {
        const int j = 4 * t + e;
        const float4 sa = *(const float4*)(S2 + j * HEADS);
        const float4 sb = *(const float4*)(S2 + j * HEADS + 4);
        const bool msk = aj[e] > 0;
        const float s2v[8] = {sa.x, sa.y, sa.z, sa.w,
                              sb.x, sb.y, sb.z, sb.w};
        #pragma unroll
        for (int h = 0; h < HEADS; ++h) {
            const float x  = s1r[h] + s2v[h];
            const float pe = msk ? __expf(lrelu(x)) : 0.f;
            p[e][h] = pe;
            ls[h]  += pe;
        }
    }

    // wave butterfly + cross-wave reduce → LFs[h]
    #pragma unroll
    for (int h = 0; h < HEADS; ++h) {
        float v = ls[h];
        #pragma unroll
        for (int off = 32; off; off >>= 1)
            v += __shfl_xor(v, off);
        if (lane == 0) redL[wave * HEADS + h] = v;
    }
    __syncthreads();

    if (t < HEADS) {
        float v = 0.f;
        #pragma unroll
        for (int w = 0; w < 8; ++w)
            v += redL[w * HEADS + t];
        LFs[t] = v;
    }
    __syncthreads();

    // ---- hh/LF: block-uniform → scalar registers -----------------------
    float hh_s[HID];
    #pragma unroll
    for (int h = 0; h < HEADS; ++h) {
        const float inv = 1.0f / LFs[h];
        #pragma unroll
        for (int d = 0; d < ODIM; ++d)
            hh_s[h * ODIM + d] = rfl(hhS[h * ODIM + d] * inv);
    }

    // ---- pass B: scale + accumulate + stream out -----------------------
    #pragma unroll
    for (int e = 0; e < 4; ++e) {
        const int j = 4 * t + e;

        float o[ODIM];
        #pragma unroll
        for (int d = 0; d < ODIM; ++d) o[d] = 0.f;
        #pragma unroll
        for (int h = 0; h < HEADS; ++h) {
            #pragma unroll
            for (int d = 0; d < ODIM; ++d)
                o[d] = fmaf(p[e][h], hh_s[h * ODIM + d], o[d]);
        }

        const size_t base = ((size_t)i * NN + j) * ODIM;
        float4 o0, o1;
        o0.x = lrelu(o[0]); o0.y = lrelu(o[1]);
        o0.z = lrelu(o[2]); o0.w = lrelu(o[3]);
        o1.x = lrelu(o[4]); o1.y = lrelu(o[5]);
        o1.z = lrelu(o[6]); o1.w = lrelu(o[7]);
        *(float4*)(out + base)     = o0;   // wave writes 8 KB contiguous
        *(float4*)(out + base + 4) = o1;
    }
}

// ---------------------------------------------------------------------------
extern "C" void kernel_launch(void* const* d_in, const int* in_sizes, int n_in,
                              void* d_out, int out_size, void* d_ws, size_t ws_size,
                              hipStream_t stream) {
    const float* X  = (const float*)d_in[0];   // (2048,128) fp32
    const int*   A  = (const int*)  d_in[1];   // (2048,2048) int32
    const float* W  = (const float*)d_in[2];   // (128,64) fp32
    const float* ak = (const float*)d_in[3];   // (16,1) fp32
    float* out = (float*)d_out;                // (2048*2048*8) fp32

    // workspace layout: H (512 KB) | S1 (64 KB) | S2 (64 KB)
    float* H  = (float*)d_ws;
    float* S1 = H  + (size_t)NN * HID;
    float* S2 = S1 + (size_t)NN * HEADS;

    gat_prep <<<NN,  64, 0, stream>>>(X, W, ak, H, S1, S2);
    gat_fused<<<NN, 512, 0, stream>>>(A, H, S1, S2, out);
}

// Round 4
// 185.358 us; speedup vs baseline: 1.1797x; 1.1797x over previous
//
#include <hip/hip_runtime.h>

// Problem constants (reference: N=2048, F=128, HEADS=8, OUT_DIM=8, ALPHA=0.2)
#define NN      2048
#define FDIM    128
#define HEADS   8
#define ODIM    8
#define HID     64      // HEADS*ODIM
#define ALPHA   0.2f

__device__ __forceinline__ float lrelu(float x) {
    return x > 0.f ? x : ALPHA * x;
}

// readfirstlane for float: value must be wave-uniform (it is: per-block row data)
__device__ __forceinline__ float rfl(float x) {
    return __int_as_float(__builtin_amdgcn_readfirstlane(__float_as_int(x)));
}

// ---------------------------------------------------------------------------
// Kernel 1: h = X @ W  (per-node row), s1 = h . a1, s2 = h . a2  (per head)
// grid = NN blocks, block = 64 threads (1 wave)
// ---------------------------------------------------------------------------
__global__ __launch_bounds__(64) void gat_prep(
        const float* __restrict__ X,   // (NN, FDIM)
        const float* __restrict__ W,   // (FDIM, HID)
        const float* __restrict__ ak,  // (2*ODIM,)
        float* __restrict__ H,         // (NN, HID)
        float* __restrict__ S1,        // (NN, HEADS)
        float* __restrict__ S2) {      // (NN, HEADS)
    const int n = blockIdx.x;
    const int t = threadIdx.x;

    __shared__ float Xs[FDIM];
    __shared__ float hs[HID];

    Xs[t]      = X[(size_t)n * FDIM + t];
    Xs[t + 64] = X[(size_t)n * FDIM + 64 + t];
    __syncthreads();

    float acc = 0.f;
    #pragma unroll 8
    for (int k = 0; k < FDIM; ++k)
        acc = fmaf(Xs[k], W[k * HID + t], acc);   // Xs[k]: LDS broadcast; W col: coalesced

    H[(size_t)n * HID + t] = acc;
    hs[t] = acc;
    __syncthreads();

    if (t < 16) {
        const int head = t & 7;
        const float* a = ak + ((t < 8) ? 0 : ODIM);
        float s = 0.f;
        #pragma unroll
        for (int d = 0; d < ODIM; ++d)
            s = fmaf(hs[head * ODIM + d], a[d], s);
        if (t < 8) S1[n * HEADS + head] = s;
        else       S2[n * HEADS + head] = s;
    }
}

// ---------------------------------------------------------------------------
// Kernel 2 (fused). R4 = R3 structure with the store layout REVERTED to
// contiguous lane mapping:
//   R3 had thread t own j=4t..4t+3 → float4 stores at 128-B lane stride →
//   16 B per 64-B sector per instruction → partial-sector evictions →
//   WRITE_SIZE 198 MB (1.48x ideal), 2.2 TB/s. Measured, not guessed.
//   Now j = t + jj*512 → 32-B lane stride, wave covers 2 KB contiguous per
//   store pair (R1 measured this layout at 1.1x ideal WRITE_SIZE).
// Kept from R3 (verified: VGPR=44, SGPR=80, no scratch):
//   - p computed ONCE, held in 32 VGPRs across both passes
//   - hh/LF and s1 wave-uniform in SGPRs via readfirstlane
//   - A read straight from global (L3-resident; FETCH was only 9.6 MB)
// grid = NN blocks, block = 512 (8 waves), 4 j per thread
// ---------------------------------------------------------------------------
__global__ __launch_bounds__(512, 4) void gat_fused(
        const int*   __restrict__ A,    // (NN, NN)
        const float* __restrict__ H,    // (NN, HID)
        const float* __restrict__ S1,   // (NN, HEADS)
        const float* __restrict__ S2,   // (NN, HEADS)
        float* __restrict__ out) {      // (NN, NN, ODIM)
    const int i    = blockIdx.x;
    const int t    = threadIdx.x;
    const int wave = t >> 6;
    const int lane = t & 63;

    __shared__ float hhS[HID];
    __shared__ float redL[8 * HEADS];
    __shared__ float LFs[HEADS];

    if (t < HID)
        hhS[t] = H[(size_t)i * HID + t];

    // s1: block-uniform → scalar registers
    float s1r[HEADS];
    #pragma unroll
    for (int h = 0; h < HEADS; ++h)
        s1r[h] = rfl(S1[i * HEADS + h]);

    // ---- pass A: compute p once (32 VGPRs), accumulate denominators ----
    float p[4][HEADS];
    float ls[HEADS];
    #pragma unroll
    for (int h = 0; h < HEADS; ++h) ls[h] = 0.f;

    #pragma unroll
    for (int jj = 0; jj < 4; ++jj) {
        const int j = t + jj * 512;              // contiguous lane mapping
        const int  msk_i = A[(size_t)i * NN + j]; // coalesced dword, L3-hit
        const float4 sa = *(const float4*)(S2 + j * HEADS);
        const float4 sb = *(const float4*)(S2 + j * HEADS + 4);
        const bool msk = msk_i > 0;
        const float s2v[8] = {sa.x, sa.y, sa.z, sa.w,
                              sb.x, sb.y, sb.z, sb.w};
        #pragma unroll
        for (int h = 0; h < HEADS; ++h) {
            const float x  = s1r[h] + s2v[h];
            const float pe = msk ? __expf(lrelu(x)) : 0.f;
            p[jj][h] = pe;
            ls[h]   += pe;
        }
    }

    // wave butterfly + cross-wave reduce → LFs[h]
    #pragma unroll
    for (int h = 0; h < HEADS; ++h) {
        float v = ls[h];
        #pragma unroll
        for (int off = 32; off; off >>= 1)
            v += __shfl_xor(v, off);
        if (lane == 0) redL[wave * HEADS + h] = v;
    }
    __syncthreads();

    if (t < HEADS) {
        float v = 0.f;
        #pragma unroll
        for (int w = 0; w < 8; ++w)
            v += redL[w * HEADS + t];
        LFs[t] = v;
    }
    __syncthreads();

    // ---- hh/LF: block-uniform → scalar registers -----------------------
    float hh_s[HID];
    #pragma unroll
    for (int h = 0; h < HEADS; ++h) {
        const float inv = 1.0f / LFs[h];
        #pragma unroll
        for (int d = 0; d < ODIM; ++d)
            hh_s[h * ODIM + d] = rfl(hhS[h * ODIM + d] * inv);
    }

    // ---- pass B: scale + accumulate + stream out -----------------------
    #pragma unroll
    for (int jj = 0; jj < 4; ++jj) {
        const int j = t + jj * 512;

        float o[ODIM];
        #pragma unroll
        for (int d = 0; d < ODIM; ++d) o[d] = 0.f;
        #pragma unroll
        for (int h = 0; h < HEADS; ++h) {
            #pragma unroll
            for (int d = 0; d < ODIM; ++d)
                o[d] = fmaf(p[jj][h], hh_s[h * ODIM + d], o[d]);
        }

        const size_t base = ((size_t)i * NN + j) * ODIM;
        float4 o0, o1;
        o0.x = lrelu(o[0]); o0.y = lrelu(o[1]);
        o0.z = lrelu(o[2]); o0.w = lrelu(o[3]);
        o1.x = lrelu(o[4]); o1.y = lrelu(o[5]);
        o1.z = lrelu(o[6]); o1.w = lrelu(o[7]);
        *(float4*)(out + base)     = o0;   // 32-B lane stride, full sectors
        *(float4*)(out + base + 4) = o1;
    }
}

// ---------------------------------------------------------------------------
extern "C" void kernel_launch(void* const* d_in, const int* in_sizes, int n_in,
                              void* d_out, int out_size, void* d_ws, size_t ws_size,
                              hipStream_t stream) {
    const float* X  = (const float*)d_in[0];   // (2048,128) fp32
    const int*   A  = (const int*)  d_in[1];   // (2048,2048) int32
    const float* W  = (const float*)d_in[2];   // (128,64) fp32
    const float* ak = (const float*)d_in[3];   // (16,1) fp32
    float* out = (float*)d_out;                // (2048*2048*8) fp32

    // workspace layout: H (512 KB) | S1 (64 KB) | S2 (64 KB)
    float* H  = (float*)d_ws;
    float* S1 = H  + (size_t)NN * HID;
    float* S2 = S1 + (size_t)NN * HEADS;

    gat_prep <<<NN,  64, 0, stream>>>(X, W, ak, H, S1, S2);
    gat_fused<<<NN, 512, 0, stream>>>(A, H, S1, S2, out);
}